// Round 1
// baseline (721.075 us; speedup 1.0000x reference)
//
#include <hip/hip_runtime.h>

// Problem: out[s][o] = sum_i x[s][i] * dq(w[o][i])
// dq: symmetric int4 group quant, group=256 along i, scale = max(absmax/7, 1e-9)
// x: [16, 4096] fp32, w: [14336, 4096] fp32, out: [16, 14336] fp32
//
// Memory-bound: 235 MB weight read dominates -> target ~37 us @ 6.3 TB/s.

constexpr int O_DIM = 14336;
constexpr int I_DIM = 4096;
constexpr int S_DIM = 16;
constexpr int GS    = 256;           // quant group size
constexpr int NG    = I_DIM / GS;    // 16 groups per row
constexpr int RPW   = 4;             // rows per wave
constexpr int NWAVE = 4;             // waves per block
constexpr int RPB   = RPW * NWAVE;   // 16 rows per block

__global__ __launch_bounds__(256, 3)
void qlin_kernel(const float* __restrict__ x,
                 const float* __restrict__ w,
                 float* __restrict__ out)
{
    // double-buffered x tile: 2 * 16 s * 256 i * 4B = 32 KB
    __shared__ float xs[2][S_DIM][GS];

    const int tid  = threadIdx.x;
    const int lane = tid & 63;
    const int wv   = tid >> 6;
    const int row0 = blockIdx.x * RPB + wv * RPW;

    // staging map: float4 slot j = k*256 + tid  ->  s = j>>6, i_off = (j&63)*4
    // (per-wave: 64 consecutive float4 of one x row -> perfectly coalesced)
    int sj[4], ij[4];
#pragma unroll
    for (int k = 0; k < 4; ++k) {
        int j = k * 256 + tid;
        sj[k] = j >> 6;
        ij[k] = (j & 63) * 4;
    }

    float4 xreg[4];            // staged x tile (in flight)
    float4 wcur[RPW], wnext[RPW];

    auto load_x_tile = [&](int g, float4* dst) {
#pragma unroll
        for (int k = 0; k < 4; ++k)
            dst[k] = *reinterpret_cast<const float4*>(
                &x[sj[k] * I_DIM + g * GS + ij[k]]);
    };
    auto load_w_tile = [&](int g, float4* dst) {
#pragma unroll
        for (int r = 0; r < RPW; ++r)
            dst[r] = *reinterpret_cast<const float4*>(
                &w[(row0 + r) * I_DIM + g * GS + lane * 4]);
    };
    auto store_x_tile = [&](int buf, const float4* src) {
#pragma unroll
        for (int k = 0; k < 4; ++k)
            *reinterpret_cast<float4*>(&xs[buf][sj[k]][ij[k]]) = src[k];
    };

    float acc[RPW][S_DIM];
#pragma unroll
    for (int r = 0; r < RPW; ++r)
#pragma unroll
        for (int s = 0; s < S_DIM; ++s) acc[r][s] = 0.0f;

    // ---- prologue: tile 0 staged, tile 1 prefetched ----
    load_x_tile(0, xreg);
    load_w_tile(0, wcur);
    store_x_tile(0, xreg);
    load_x_tile(1, xreg);
    load_w_tile(1, wnext);
    __syncthreads();

    for (int g = 0; g < NG; ++g) {
        const int buf = g & 1;

        // ---- dequantize current w tile ----
        float4 dq[RPW];
#pragma unroll
        for (int r = 0; r < RPW; ++r) {
            float4 v = wcur[r];
            float m = fmaxf(fmaxf(fabsf(v.x), fabsf(v.y)),
                            fmaxf(fabsf(v.z), fabsf(v.w)));
#pragma unroll
            for (int off = 1; off < 64; off <<= 1)
                m = fmaxf(m, __shfl_xor(m, off, 64));
            float scale = fmaxf(m * (1.0f / 7.0f), 1e-9f);
            float invs  = 1.0f / scale;
            float qx = fminf(fmaxf(rintf(v.x * invs), -8.0f), 7.0f);
            float qy = fminf(fmaxf(rintf(v.y * invs), -8.0f), 7.0f);
            float qz = fminf(fmaxf(rintf(v.z * invs), -8.0f), 7.0f);
            float qw = fminf(fmaxf(rintf(v.w * invs), -8.0f), 7.0f);
            dq[r] = make_float4(qx * scale, qy * scale, qz * scale, qw * scale);
        }

        // ---- FMA inner loop: each ds_read_b128 feeds 16 fmas ----
#pragma unroll
        for (int s = 0; s < S_DIM; ++s) {
            float4 xv = *reinterpret_cast<const float4*>(&xs[buf][s][lane * 4]);
#pragma unroll
            for (int r = 0; r < RPW; ++r) {
                acc[r][s] = fmaf(dq[r].x, xv.x, acc[r][s]);
                acc[r][s] = fmaf(dq[r].y, xv.y, acc[r][s]);
                acc[r][s] = fmaf(dq[r].z, xv.z, acc[r][s]);
                acc[r][s] = fmaf(dq[r].w, xv.w, acc[r][s]);
            }
        }

        if (g + 1 < NG) {
            // write prefetched tile g+1 into the other buffer
            // (safe: buf^1 last read in iter g-1, fenced by that iter's sync)
            store_x_tile(buf ^ 1, xreg);
#pragma unroll
            for (int r = 0; r < RPW; ++r) wcur[r] = wnext[r];
            if (g + 2 < NG) {
                load_x_tile(g + 2, xreg);   // in flight across next iteration
                load_w_tile(g + 2, wnext);
            }
            __syncthreads();
        }
    }

    // ---- epilogue: reduce each (r,s) across the 64 lanes, scatter-write ----
#pragma unroll
    for (int r = 0; r < RPW; ++r) {
        const int o = row0 + r;
#pragma unroll
        for (int s = 0; s < S_DIM; ++s) {
            float v = acc[r][s];
#pragma unroll
            for (int off = 1; off < 64; off <<= 1)
                v += __shfl_xor(v, off, 64);
            if (lane == s) out[s * O_DIM + o] = v;
        }
    }
}

extern "C" void kernel_launch(void* const* d_in, const int* in_sizes, int n_in,
                              void* d_out, int out_size, void* d_ws, size_t ws_size,
                              hipStream_t stream) {
    const float* x = (const float*)d_in[0];   // 1*16*4096
    const float* w = (const float*)d_in[1];   // 14336*4096
    float* out = (float*)d_out;               // 16*14336
    dim3 grid(O_DIM / RPB);                   // 896 blocks
    dim3 block(256);
    qlin_kernel<<<grid, block, 0, stream>>>(x, w, out);
}

// Round 2
// 374.596 us; speedup vs baseline: 1.9249x; 1.9249x over previous
//
#include <hip/hip_runtime.h>

// out[s][o] = sum_i x[s][i] * dq(w[o][i]); int4 group quant, group=256, scale=max(absmax/7,1e-9)
// x: [16,4096] f32 (cache-resident), w: [14336,4096] f32 (235 MB, read once), out: [16,14336] f32
//
// R2: no LDS, no barriers. Latency hidden by true in-flight w prefetch +
// 7 blocks/CU. x read straight from global (L1/L2-hit). HBM floor ~39 us.

constexpr int O_DIM = 14336;
constexpr int I_DIM = 4096;
constexpr int S_DIM = 16;
constexpr int GS    = 256;          // quant group size
constexpr int NG    = I_DIM / GS;   // 16
constexpr int RPW   = 4;            // rows per wave
constexpr int NWAVE = 2;            // waves per block (128 threads)
constexpr int RPB   = RPW * NWAVE;  // 8 rows/block -> 1792 blocks = 7/CU

__global__ __launch_bounds__(128, 3)   // cap ~168 VGPR; 12 waves/CU min
void qlin_kernel(const float* __restrict__ x,
                 const float* __restrict__ w,
                 float* __restrict__ out)
{
    const int tid  = threadIdx.x;
    const int lane = tid & 63;
    const int wv   = tid >> 6;
    const int row0 = blockIdx.x * RPB + wv * RPW;

    const float* wp = w + (size_t)row0 * I_DIM + lane * 4;
    const float* xp = x + lane * 4;

    float acc[RPW][S_DIM];
#pragma unroll
    for (int r = 0; r < RPW; ++r)
#pragma unroll
        for (int s = 0; s < S_DIM; ++s) acc[r][s] = 0.0f;

    float4 wcur[RPW], wnext[RPW];
#pragma unroll
    for (int r = 0; r < RPW; ++r)
        wcur[r] = *reinterpret_cast<const float4*>(wp + (size_t)r * I_DIM);

    for (int g = 0; g < NG; ++g) {
        const int base = g * GS;

        // ---- issue next group's w loads first (HBM, longest latency) ----
        if (g + 1 < NG) {
#pragma unroll
            for (int r = 0; r < RPW; ++r)
                wnext[r] = *reinterpret_cast<const float4*>(
                    wp + (size_t)r * I_DIM + base + GS);
        }

        // ---- x batch 0 in flight (L1/L2 hit) ----
        float4 xv[4], xn[4];
#pragma unroll
        for (int k = 0; k < 4; ++k)
            xv[k] = *reinterpret_cast<const float4*>(xp + (size_t)k * I_DIM + base);

        // ---- dequantize current w (group absmax via 64-lane butterfly) ----
        float4 dq[RPW];
#pragma unroll
        for (int r = 0; r < RPW; ++r) {
            float4 v = wcur[r];
            float m = fmaxf(fmaxf(fabsf(v.x), fabsf(v.y)),
                            fmaxf(fabsf(v.z), fabsf(v.w)));
#pragma unroll
            for (int off = 1; off < 64; off <<= 1)
                m = fmaxf(m, __shfl_xor(m, off, 64));
            float scale = fmaxf(m * (1.0f / 7.0f), 1e-9f);
            float invs  = 1.0f / scale;
            dq[r].x = fminf(fmaxf(rintf(v.x * invs), -8.0f), 7.0f) * scale;
            dq[r].y = fminf(fmaxf(rintf(v.y * invs), -8.0f), 7.0f) * scale;
            dq[r].z = fminf(fmaxf(rintf(v.z * invs), -8.0f), 7.0f) * scale;
            dq[r].w = fminf(fmaxf(rintf(v.w * invs), -8.0f), 7.0f) * scale;
        }

        // ---- FMA over 16 s, register-double-buffered x batches of 4 ----
#pragma unroll
        for (int sb = 0; sb < S_DIM; sb += 4) {
            if (sb + 4 < S_DIM) {
#pragma unroll
                for (int k = 0; k < 4; ++k)
                    xn[k] = *reinterpret_cast<const float4*>(
                        xp + (size_t)(sb + 4 + k) * I_DIM + base);
            }
#pragma unroll
            for (int k = 0; k < 4; ++k) {
                const int s = sb + k;
#pragma unroll
                for (int r = 0; r < RPW; ++r) {
                    acc[r][s] = fmaf(dq[r].x, xv[k].x, acc[r][s]);
                    acc[r][s] = fmaf(dq[r].y, xv[k].y, acc[r][s]);
                    acc[r][s] = fmaf(dq[r].z, xv[k].z, acc[r][s]);
                    acc[r][s] = fmaf(dq[r].w, xv[k].w, acc[r][s]);
                }
            }
#pragma unroll
            for (int k = 0; k < 4; ++k) xv[k] = xn[k];
        }

#pragma unroll
        for (int r = 0; r < RPW; ++r) wcur[r] = wnext[r];
    }

    // ---- epilogue: 64-lane butterfly per (r,s); lane s stores ----
#pragma unroll
    for (int r = 0; r < RPW; ++r) {
        const int o = row0 + r;
#pragma unroll
        for (int s = 0; s < S_DIM; ++s) {
            float v = acc[r][s];
#pragma unroll
            for (int off = 1; off < 64; off <<= 1)
                v += __shfl_xor(v, off, 64);
            if (lane == s) out[s * O_DIM + o] = v;
        }
    }
}

extern "C" void kernel_launch(void* const* d_in, const int* in_sizes, int n_in,
                              void* d_out, int out_size, void* d_ws, size_t ws_size,
                              hipStream_t stream) {
    const float* x = (const float*)d_in[0];   // 1*16*4096
    const float* w = (const float*)d_in[1];   // 14336*4096
    float* out = (float*)d_out;               // 16*14336
    dim3 grid(O_DIM / RPB);                   // 1792 blocks
    dim3 block(128);
    qlin_kernel<<<grid, block, 0, stream>>>(x, w, out);
}